// Round 1
// baseline (926.410 us; speedup 1.0000x reference)
//
#include <hip/hip_runtime.h>
#include <hip/hip_bf16.h>
#include <stdint.h>

// Problem constants (B=2048, N=128, D=512, E=64)
#define Bb 2048
#define Nn 128
#define Dd 512
#define Ee 64
#define Mm (Bb * Nn)   // 262144 positions

typedef __bf16 bf16t;
typedef bf16t bf16x8 __attribute__((ext_vector_type(8)));
typedef float f32x4 __attribute__((ext_vector_type(4)));

union AFrag { bf16x8 v; uint32_t d[4]; };
union BFrag { bf16x8 v; uint4 q; };

// ---------------- kernel 0: split w_gate into bf16 hi/lo ----------------
__global__ __launch_bounds__(256) void k_packw(const float* __restrict__ w,
                                               uint16_t* __restrict__ whi,
                                               uint16_t* __restrict__ wlo) {
  int i = blockIdx.x * 256 + threadIdx.x;
  if (i < Ee * Dd) {
    float v = w[i];
    uint32_t ub = __float_as_uint(v);
    uint32_t h = ub >> 16;                      // truncation is fine: lo compensates
    float rest = v - __uint_as_float(h << 16);
    whi[i] = (uint16_t)h;
    wlo[i] = (uint16_t)(__float_as_uint(rest) >> 16);
  }
}

// ---------------- kernel: zero the tiny accumulators ----------------
__global__ void k_zero(float* denomS, float* cntS) {
  int t = threadIdx.x;
  if (t < Ee) { denomS[t] = 0.f; cntS[t] = 0.f; }
}

// ---------------- kernel 1: GEMM + softmax stats + zero-fill output ----------------
// Block = 256 threads = 4 waves. Each wave: 16 positions x 64 experts via
// 4 col-tiles of mfma_f32_16x16x32_bf16, 3 MFMAs per tile (hi*hi + hi*lo + lo*hi).
__global__ __launch_bounds__(256) void k_main(const float* __restrict__ x,
    const uint16_t* __restrict__ whi, const uint16_t* __restrict__ wlo,
    const float* __restrict__ bg,
    float* __restrict__ out, float* __restrict__ gate0, int* __restrict__ amax)
{
  int tid = threadIdx.x;
  int wave = tid >> 6, lane = tid & 63;
  int l15 = lane & 15, quad = lane >> 4;

  // Fused zero-fill of this block's 64 output rows (64*64 floats = 1024 float4)
  {
    float4 z = make_float4(0.f, 0.f, 0.f, 0.f);
    float4* ob = (float4*)(out) + (size_t)blockIdx.x * 1024;
    #pragma unroll
    for (int i = 0; i < 4; ++i) ob[tid + 256 * i] = z;
  }

  size_t p0 = (size_t)blockIdx.x * 64 + (size_t)wave * 16;  // wave's first row
  const float* xrow = x + (p0 + (size_t)l15) * Dd + quad * 8;

  f32x4 acc[4];
  #pragma unroll
  for (int ct = 0; ct < 4; ++ct) acc[ct] = (f32x4){0.f, 0.f, 0.f, 0.f};

  for (int kt = 0; kt < Dd; kt += 32) {
    // A fragment: x[p][kt + quad*8 .. +7] as f32, split into bf16 hi/lo
    float4 a0 = *(const float4*)(xrow + kt);
    float4 a1 = *(const float4*)(xrow + kt + 4);
    float av[8] = {a0.x, a0.y, a0.z, a0.w, a1.x, a1.y, a1.z, a1.w};
    AFrag ahi, alo;
    #pragma unroll
    for (int j = 0; j < 4; ++j) {
      uint32_t u0 = __float_as_uint(av[2 * j]);
      uint32_t u1 = __float_as_uint(av[2 * j + 1]);
      uint32_t h0 = u0 >> 16, h1 = u1 >> 16;
      float r0 = av[2 * j]     - __uint_as_float(h0 << 16);
      float r1 = av[2 * j + 1] - __uint_as_float(h1 << 16);
      uint32_t lo0 = __float_as_uint(r0) >> 16;
      uint32_t lo1 = __float_as_uint(r1) >> 16;
      ahi.d[j] = h0 | (h1 << 16);
      alo.d[j] = lo0 | (lo1 << 16);
    }
    #pragma unroll
    for (int ct = 0; ct < 4; ++ct) {
      int c = ct * 16 + l15;  // expert row
      BFrag bh, bl;
      bh.q = *(const uint4*)(whi + (size_t)c * Dd + kt + quad * 8);
      bl.q = *(const uint4*)(wlo + (size_t)c * Dd + kt + quad * 8);
      acc[ct] = __builtin_amdgcn_mfma_f32_16x16x32_bf16(ahi.v, bh.v, acc[ct], 0, 0, 0);
      acc[ct] = __builtin_amdgcn_mfma_f32_16x16x32_bf16(ahi.v, bl.v, acc[ct], 0, 0, 0);
      acc[ct] = __builtin_amdgcn_mfma_f32_16x16x32_bf16(alo.v, bh.v, acc[ct], 0, 0, 0);
    }
  }

  // Epilogue: logits for rows r = quad*4+reg, cols c = ct*16+l15.
  float bia[4];
  #pragma unroll
  for (int ct = 0; ct < 4; ++ct) bia[ct] = bg[ct * 16 + l15];

  #pragma unroll
  for (int reg = 0; reg < 4; ++reg) {
    float v[4];
    #pragma unroll
    for (int ct = 0; ct < 4; ++ct) v[ct] = acc[ct][reg] + bia[ct];

    // argmax over 64 cols: local over 4 col-tiles (strictly-greater keeps lowest c),
    // then butterfly over the 16-lane group (xor 1,2,4,8 stays in-group).
    float mx = v[0]; int mi = l15;
    #pragma unroll
    for (int ct = 1; ct < 4; ++ct) {
      int c = ct * 16 + l15;
      if (v[ct] > mx) { mx = v[ct]; mi = c; }
    }
    #pragma unroll
    for (int off = 1; off < 16; off <<= 1) {
      float om = __shfl_xor(mx, off);
      int   oi = __shfl_xor(mi, off);
      if (om > mx || (om == mx && oi < mi)) { mx = om; mi = oi; }
    }
    // softmax denominator
    float s = 0.f;
    #pragma unroll
    for (int ct = 0; ct < 4; ++ct) s += expf(v[ct] - mx);
    #pragma unroll
    for (int off = 1; off < 16; off <<= 1) s += __shfl_xor(s, off);

    if (l15 == 0) {   // this lane holds col 0 (v[0])
      size_t pr = p0 + (size_t)quad * 4 + reg;
      gate0[pr] = expf(v[0] - mx) / s;
      amax[pr]  = mi;
    }
  }
}

// ---------------- kernel 2: per-batch coverage + denominator accumulation ----------------
__global__ __launch_bounds__(64) void k_cov(const int* __restrict__ amax,
                                            const float* __restrict__ gate0,
                                            unsigned long long* __restrict__ covbits,
                                            float* __restrict__ denomS,
                                            float* __restrict__ cntS) {
  int b = blockIdx.x;
  int lane = threadIdx.x;  // lane == seq-slot m in [0,64)
  __shared__ int idxs[Nn];
  idxs[lane]      = amax[(size_t)b * Nn + lane];
  idxs[lane + 64] = amax[(size_t)b * Nn + 64 + lane];
  __syncthreads();
  bool cov = false;
  #pragma unroll 8
  for (int n = 0; n < Nn; ++n) cov |= (idxs[n] == lane);
  unsigned long long bits = __ballot(cov);
  if (lane == 0) covbits[b] = bits;
  if (cov) {
    atomicAdd(&denomS[lane], gate0[(size_t)b * Nn + lane]);
    atomicAdd(&cntS[lane], 1.0f);
  }
}

// ---------------- kernel 3: scatter the covered gs values ----------------
__global__ __launch_bounds__(64) void k_scatter(const float* __restrict__ gate0,
                                                const unsigned long long* __restrict__ covbits,
                                                const float* __restrict__ denomS,
                                                float* __restrict__ out) {
  int b = blockIdx.x;
  int n = threadIdx.x;  // n < 64
  if ((covbits[b] >> n) & 1ull) {
    float g = gate0[(size_t)b * Nn + n];
    out[((size_t)(b * Nn + n)) * Ee] = g * 2048.0f / (denomS[n] + 1e-6f);
  }
}

// ---------------- kernel 4: closed-form cv^2 loss ----------------
__global__ __launch_bounds__(64) void k_loss(const float* __restrict__ denomS,
                                             const float* __restrict__ cntS,
                                             float* __restrict__ out) {
  int lane = threadIdx.x;
  double S = (double)denomS[lane];
  double imp = S / (S + 1e-6) * 2048.0;   // 0 when S==0
  double ld = (double)cntS[lane];
  double s1i = imp, s2i = imp * imp, s1l = ld, s2l = ld * ld;
  #pragma unroll
  for (int off = 1; off < 64; off <<= 1) {
    s1i += __shfl_xor(s1i, off);
    s2i += __shfl_xor(s2i, off);
    s1l += __shfl_xor(s1l, off);
    s2l += __shfl_xor(s2l, off);
  }
  if (lane == 0) {
    const double Nt = (double)(Nn * Ee);  // 8192 elements in [N,E]
    double mi_ = s1i / Nt;
    double vi  = (s2i - Nt * mi_ * mi_) / (Nt - 1.0);
    double li  = vi / (mi_ * mi_ + 1e-10);
    double ml_ = s1l / Nt;
    double vl  = (s2l - Nt * ml_ * ml_) / (Nt - 1.0);
    double ll_ = vl / (ml_ * ml_ + 1e-10);
    out[(size_t)Mm * Ee] = (float)(li + ll_);
  }
}

extern "C" void kernel_launch(void* const* d_in, const int* in_sizes, int n_in,
                              void* d_out, int out_size, void* d_ws, size_t ws_size,
                              hipStream_t stream) {
  const float* x  = (const float*)d_in[0];
  const float* w  = (const float*)d_in[1];
  const float* bg = (const float*)d_in[2];
  float* out = (float*)d_out;

  // Workspace layout (~2.2 MB total)
  char* ws = (char*)d_ws;
  float* gate0 = (float*)ws;                                      // 1 MB
  int*   amax  = (int*)(ws + (size_t)Mm * 4);                     // 1 MB
  unsigned long long* covbits =
      (unsigned long long*)(ws + (size_t)Mm * 8);                 // 16 KB
  float* denomS = (float*)(ws + (size_t)Mm * 8 + (size_t)Bb * 8); // 256 B
  float* cntS   = denomS + Ee;                                    // 256 B
  uint16_t* whi = (uint16_t*)(denomS + 2 * Ee);                   // 64 KB
  uint16_t* wlo = whi + Ee * Dd;                                  // 64 KB

  k_packw<<<(Ee * Dd + 255) / 256, 256, 0, stream>>>(w, whi, wlo);
  k_zero<<<1, 64, 0, stream>>>(denomS, cntS);
  k_main<<<Mm / 64, 256, 0, stream>>>(x, whi, wlo, bg, out, gate0, amax);
  k_cov<<<Bb, 64, 0, stream>>>(amax, gate0, covbits, denomS, cntS);
  k_scatter<<<Bb, 64, 0, stream>>>(gate0, covbits, denomS, out);
  k_loss<<<1, 64, 0, stream>>>(denomS, cntS, out);
}

// Round 2
// 882.477 us; speedup vs baseline: 1.0498x; 1.0498x over previous
//
#include <hip/hip_runtime.h>
#include <hip/hip_bf16.h>
#include <stdint.h>

// Problem constants (B=2048, N=128, D=512, E=64)
#define Bb 2048
#define Nn 128
#define Dd 512
#define Ee 64
#define Mm (Bb * Nn)   // 262144 positions

typedef __bf16 bf16t;
typedef bf16t bf16x8 __attribute__((ext_vector_type(8)));
typedef float f32x4 __attribute__((ext_vector_type(4)));

union AFrag { bf16x8 v; uint32_t d[4]; };
union BFrag { bf16x8 v; uint4 q; };

// ---------------- kernel 0: split w_gate into bf16 hi/lo ----------------
__global__ __launch_bounds__(256) void k_packw(const float* __restrict__ w,
                                               uint16_t* __restrict__ whi,
                                               uint16_t* __restrict__ wlo) {
  int i = blockIdx.x * 256 + threadIdx.x;
  if (i < Ee * Dd) {
    float v = w[i];
    uint32_t ub = __float_as_uint(v);
    uint32_t h = ub >> 16;                      // truncation is fine: lo compensates
    float rest = v - __uint_as_float(h << 16);
    whi[i] = (uint16_t)h;
    wlo[i] = (uint16_t)(__float_as_uint(rest) >> 16);
  }
}

// ---------------- kernel 1: GEMM + softmax stats + zero-fill output ----------------
// Block = 256 threads = 4 waves. Each wave: 16 positions x 64 experts via
// 4 col-tiles of mfma_f32_16x16x32_bf16, 3 MFMAs per tile (hi*hi + hi*lo + lo*hi).
__global__ __launch_bounds__(256) void k_main(const float* __restrict__ x,
    const uint16_t* __restrict__ whi, const uint16_t* __restrict__ wlo,
    const float* __restrict__ bg,
    float* __restrict__ out, float* __restrict__ gate0, int* __restrict__ amax)
{
  int tid = threadIdx.x;
  int wave = tid >> 6, lane = tid & 63;
  int l15 = lane & 15, quad = lane >> 4;

  // Fused zero-fill of this block's 64 output rows (64*64 floats = 1024 float4)
  {
    float4 z = make_float4(0.f, 0.f, 0.f, 0.f);
    float4* ob = (float4*)(out) + (size_t)blockIdx.x * 1024;
    #pragma unroll
    for (int i = 0; i < 4; ++i) ob[tid + 256 * i] = z;
  }

  size_t p0 = (size_t)blockIdx.x * 64 + (size_t)wave * 16;  // wave's first row
  const float* xrow = x + (p0 + (size_t)l15) * Dd + quad * 8;

  f32x4 acc[4];
  #pragma unroll
  for (int ct = 0; ct < 4; ++ct) acc[ct] = (f32x4){0.f, 0.f, 0.f, 0.f};

  for (int kt = 0; kt < Dd; kt += 32) {
    // A fragment: x[p][kt + quad*8 .. +7] as f32, split into bf16 hi/lo
    float4 a0 = *(const float4*)(xrow + kt);
    float4 a1 = *(const float4*)(xrow + kt + 4);
    float av[8] = {a0.x, a0.y, a0.z, a0.w, a1.x, a1.y, a1.z, a1.w};
    AFrag ahi, alo;
    #pragma unroll
    for (int j = 0; j < 4; ++j) {
      uint32_t u0 = __float_as_uint(av[2 * j]);
      uint32_t u1 = __float_as_uint(av[2 * j + 1]);
      uint32_t h0 = u0 >> 16, h1 = u1 >> 16;
      float r0 = av[2 * j]     - __uint_as_float(h0 << 16);
      float r1 = av[2 * j + 1] - __uint_as_float(h1 << 16);
      uint32_t lo0 = __float_as_uint(r0) >> 16;
      uint32_t lo1 = __float_as_uint(r1) >> 16;
      ahi.d[j] = h0 | (h1 << 16);
      alo.d[j] = lo0 | (lo1 << 16);
    }
    #pragma unroll
    for (int ct = 0; ct < 4; ++ct) {
      int c = ct * 16 + l15;  // expert row
      BFrag bh, bl;
      bh.q = *(const uint4*)(whi + (size_t)c * Dd + kt + quad * 8);
      bl.q = *(const uint4*)(wlo + (size_t)c * Dd + kt + quad * 8);
      acc[ct] = __builtin_amdgcn_mfma_f32_16x16x32_bf16(ahi.v, bh.v, acc[ct], 0, 0, 0);
      acc[ct] = __builtin_amdgcn_mfma_f32_16x16x32_bf16(ahi.v, bl.v, acc[ct], 0, 0, 0);
      acc[ct] = __builtin_amdgcn_mfma_f32_16x16x32_bf16(alo.v, bh.v, acc[ct], 0, 0, 0);
    }
  }

  // Epilogue: logits for rows r = quad*4+reg, cols c = ct*16+l15.
  float bia[4];
  #pragma unroll
  for (int ct = 0; ct < 4; ++ct) bia[ct] = bg[ct * 16 + l15];

  #pragma unroll
  for (int reg = 0; reg < 4; ++reg) {
    float v[4];
    #pragma unroll
    for (int ct = 0; ct < 4; ++ct) v[ct] = acc[ct][reg] + bia[ct];

    // argmax over 64 cols: local over 4 col-tiles (strictly-greater keeps lowest c),
    // then butterfly over the 16-lane group (xor 1,2,4,8 stays in-group).
    float mx = v[0]; int mi = l15;
    #pragma unroll
    for (int ct = 1; ct < 4; ++ct) {
      int c = ct * 16 + l15;
      if (v[ct] > mx) { mx = v[ct]; mi = c; }
    }
    #pragma unroll
    for (int off = 1; off < 16; off <<= 1) {
      float om = __shfl_xor(mx, off);
      int   oi = __shfl_xor(mi, off);
      if (om > mx || (om == mx && oi < mi)) { mx = om; mi = oi; }
    }
    // softmax denominator
    float s = 0.f;
    #pragma unroll
    for (int ct = 0; ct < 4; ++ct) s += expf(v[ct] - mx);
    #pragma unroll
    for (int off = 1; off < 16; off <<= 1) s += __shfl_xor(s, off);

    if (l15 == 0) {   // this lane holds col 0 (v[0])
      size_t pr = p0 + (size_t)quad * 4 + reg;
      gate0[pr] = expf(v[0] - mx) / s;
      amax[pr]  = mi;
    }
  }
}

// ---------------- kernel 2: per-batch coverage (NO atomics) ----------------
// Writes covg[b][e] = cov ? gate0[b,e] : 0, coalesced; covbits[b] for counts.
__global__ __launch_bounds__(64) void k_cov(const int* __restrict__ amax,
                                            const float* __restrict__ gate0,
                                            unsigned long long* __restrict__ covbits,
                                            float* __restrict__ covg) {
  int b = blockIdx.x;
  int lane = threadIdx.x;  // lane == seq-slot m in [0,64)
  __shared__ int idxs[Nn];
  idxs[lane]      = amax[(size_t)b * Nn + lane];
  idxs[lane + 64] = amax[(size_t)b * Nn + 64 + lane];
  __syncthreads();
  bool cov = false;
  #pragma unroll 8
  for (int n = 0; n < Nn; ++n) cov |= (idxs[n] == lane);
  unsigned long long bits = __ballot(cov);
  if (lane == 0) covbits[b] = bits;
  covg[(size_t)b * Ee + lane] = cov ? gate0[(size_t)b * Nn + lane] : 0.f;
}

// ---------------- kernel 2b: reduce covg over b -> denomS, cntS ----------------
__global__ __launch_bounds__(256) void k_reduce(const float* __restrict__ covg,
                                                const unsigned long long* __restrict__ covbits,
                                                float* __restrict__ denomS,
                                                float* __restrict__ cntS) {
  int e = blockIdx.x;       // expert / seq-slot [0,64)
  int t = threadIdx.x;
  float s = 0.f, c = 0.f;
  for (int b = t; b < Bb; b += 256) {
    s += covg[(size_t)b * Ee + e];
    c += (float)((covbits[b] >> e) & 1ull);
  }
  #pragma unroll
  for (int off = 1; off < 64; off <<= 1) {
    s += __shfl_xor(s, off);
    c += __shfl_xor(c, off);
  }
  __shared__ float ss[4], cs[4];
  int wave = t >> 6, lane = t & 63;
  if (lane == 0) { ss[wave] = s; cs[wave] = c; }
  __syncthreads();
  if (t == 0) {
    float S = 0.f, C = 0.f;
    #pragma unroll
    for (int i = 0; i < 4; ++i) { S += ss[i]; C += cs[i]; }
    denomS[e] = S;
    cntS[e] = C;
  }
}

// ---------------- kernel 3: scatter the covered gs values ----------------
__global__ __launch_bounds__(64) void k_scatter(const float* __restrict__ gate0,
                                                const unsigned long long* __restrict__ covbits,
                                                const float* __restrict__ denomS,
                                                float* __restrict__ out) {
  int b = blockIdx.x;
  int n = threadIdx.x;  // n < 64
  if ((covbits[b] >> n) & 1ull) {
    float g = gate0[(size_t)b * Nn + n];
    out[((size_t)(b * Nn + n)) * Ee] = g * 2048.0f / (denomS[n] + 1e-6f);
  }
}

// ---------------- kernel 4: closed-form cv^2 loss ----------------
__global__ __launch_bounds__(64) void k_loss(const float* __restrict__ denomS,
                                             const float* __restrict__ cntS,
                                             float* __restrict__ out) {
  int lane = threadIdx.x;
  double S = (double)denomS[lane];
  double imp = S / (S + 1e-6) * 2048.0;   // 0 when S==0
  double ld = (double)cntS[lane];
  double s1i = imp, s2i = imp * imp, s1l = ld, s2l = ld * ld;
  #pragma unroll
  for (int off = 1; off < 64; off <<= 1) {
    s1i += __shfl_xor(s1i, off);
    s2i += __shfl_xor(s2i, off);
    s1l += __shfl_xor(s1l, off);
    s2l += __shfl_xor(s2l, off);
  }
  if (lane == 0) {
    const double Nt = (double)(Nn * Ee);  // 8192 elements in [N,E]
    double mi_ = s1i / Nt;
    double vi  = (s2i - Nt * mi_ * mi_) / (Nt - 1.0);
    double li  = vi / (mi_ * mi_ + 1e-10);
    double ml_ = s1l / Nt;
    double vl  = (s2l - Nt * ml_ * ml_) / (Nt - 1.0);
    double ll_ = vl / (ml_ * ml_ + 1e-10);
    out[(size_t)Mm * Ee] = (float)(li + ll_);
  }
}

extern "C" void kernel_launch(void* const* d_in, const int* in_sizes, int n_in,
                              void* d_out, int out_size, void* d_ws, size_t ws_size,
                              hipStream_t stream) {
  const float* x  = (const float*)d_in[0];
  const float* w  = (const float*)d_in[1];
  const float* bg = (const float*)d_in[2];
  float* out = (float*)d_out;

  // Workspace layout (~2.7 MB total)
  char* ws = (char*)d_ws;
  float* gate0 = (float*)ws;                                      // 1 MB
  int*   amax  = (int*)(ws + (size_t)Mm * 4);                     // 1 MB
  unsigned long long* covbits =
      (unsigned long long*)(ws + (size_t)Mm * 8);                 // 16 KB
  float* denomS = (float*)(ws + (size_t)Mm * 8 + (size_t)Bb * 8); // 256 B
  float* cntS   = denomS + Ee;                                    // 256 B
  uint16_t* whi = (uint16_t*)(denomS + 2 * Ee);                   // 64 KB
  uint16_t* wlo = whi + Ee * Dd;                                  // 64 KB
  float* covg   = (float*)(wlo + Ee * Dd);                        // 512 KB

  k_packw<<<(Ee * Dd + 255) / 256, 256, 0, stream>>>(w, whi, wlo);
  k_main<<<Mm / 64, 256, 0, stream>>>(x, whi, wlo, bg, out, gate0, amax);
  k_cov<<<Bb, 64, 0, stream>>>(amax, gate0, covbits, covg);
  k_reduce<<<Ee, 256, 0, stream>>>(covg, covbits, denomS, cntS);
  k_scatter<<<Bb, 64, 0, stream>>>(gate0, covbits, denomS, out);
  k_loss<<<1, 64, 0, stream>>>(denomS, cntS, out);
}

// Round 3
// 754.850 us; speedup vs baseline: 1.2273x; 1.1691x over previous
//
#include <hip/hip_runtime.h>
#include <hip/hip_bf16.h>
#include <stdint.h>

// Problem constants (B=2048, N=128, D=512, E=64)
#define Bb 2048
#define Nn 128
#define Dd 512
#define Ee 64
#define Mm (Bb * Nn)   // 262144 positions

typedef __bf16 bf16t;
typedef bf16t bf16x8 __attribute__((ext_vector_type(8)));
typedef float f32x4 __attribute__((ext_vector_type(4)));

union AFrag { bf16x8 v; uint32_t d[4]; };
union BFrag { bf16x8 v; uint4 q; };

// split two f32 into packed bf16-hi (truncated) and bf16-lo (residual), 6 VALU ops
__device__ __forceinline__ void split2(float f0, float f1, uint32_t& hi, uint32_t& lo) {
  uint32_t u0 = __float_as_uint(f0), u1 = __float_as_uint(f1);
  hi = __builtin_amdgcn_perm(u1, u0, 0x07060302u);   // = hi16(u0) | hi16(u1)<<16
  float r0 = f0 - __uint_as_float(u0 & 0xffff0000u);
  float r1 = f1 - __uint_as_float(u1 & 0xffff0000u);
  lo = __builtin_amdgcn_perm(__float_as_uint(r1), __float_as_uint(r0), 0x07060302u);
}

// ---------------- kernel 0: split w_gate into bf16 hi/lo ----------------
__global__ __launch_bounds__(256) void k_packw(const float* __restrict__ w,
                                               uint16_t* __restrict__ whi,
                                               uint16_t* __restrict__ wlo) {
  int i = blockIdx.x * 256 + threadIdx.x;
  if (i < Ee * Dd) {
    float v = w[i];
    uint32_t h = __float_as_uint(v) >> 16;     // truncation is fine: lo compensates
    float rest = v - __uint_as_float(h << 16);
    whi[i] = (uint16_t)h;
    wlo[i] = (uint16_t)(__float_as_uint(rest) >> 16);
  }
}

// ---------------- kernel 1: GEMM + softmax stats + zero-fill output ----------------
// Block = 256 threads = 4 waves. Each wave: 64 positions (4 row-tiles of 16) x 64
// experts (4 col-tiles) via mfma_f32_16x16x32_bf16, 3 MFMAs per tile pair
// (hi*hi + hi*lo + lo*hi). B fragments loaded once per K-iter, reused across the
// 4 row-tiles; next K-iter's x prefetched into registers (software pipeline).
__global__ __launch_bounds__(256) void k_main(const float* __restrict__ x,
    const uint16_t* __restrict__ whi, const uint16_t* __restrict__ wlo,
    const float* __restrict__ bg,
    float* __restrict__ out, float* __restrict__ gate0, int* __restrict__ amax)
{
  int tid = threadIdx.x;
  int wave = tid >> 6, lane = tid & 63;
  int l15 = lane & 15, quad = lane >> 4;

  // Fused zero-fill of this block's 256 output rows (256*64 floats = 4096 float4)
  {
    float4 z = make_float4(0.f, 0.f, 0.f, 0.f);
    float4* ob = (float4*)(out) + (size_t)blockIdx.x * 4096;
    #pragma unroll
    for (int i = 0; i < 16; ++i) ob[tid + 256 * i] = z;
  }

  size_t prow = (size_t)blockIdx.x * 256 + (size_t)wave * 64;  // wave's first row
  const float* xp = x + (prow + (size_t)l15) * Dd + quad * 8;  // +t*16*Dd per tile

  f32x4 acc[4][4];  // [row-tile][col-tile]
  #pragma unroll
  for (int t = 0; t < 4; ++t)
    #pragma unroll
    for (int ct = 0; ct < 4; ++ct) acc[t][ct] = (f32x4){0.f, 0.f, 0.f, 0.f};

  // prefetch kt=0
  float4 an[4][2];
  #pragma unroll
  for (int t = 0; t < 4; ++t) {
    an[t][0] = *(const float4*)(xp + t * 16 * Dd);
    an[t][1] = *(const float4*)(xp + t * 16 * Dd + 4);
  }

  for (int kt = 0; kt < Dd; kt += 32) {
    int ktn = (kt + 32 < Dd) ? kt + 32 : 0;  // clamp: extra loads unused, harmless

    // B fragments for current kt (shared by all 4 row-tiles)
    BFrag bh[4], bl[4];
    #pragma unroll
    for (int ct = 0; ct < 4; ++ct) {
      int c = ct * 16 + l15;  // expert row
      bh[ct].q = *(const uint4*)(whi + (size_t)c * Dd + kt + quad * 8);
      bl[ct].q = *(const uint4*)(wlo + (size_t)c * Dd + kt + quad * 8);
    }

    // rotate prefetched A into cur; issue next iteration's loads
    float4 cur[4][2];
    #pragma unroll
    for (int t = 0; t < 4; ++t) { cur[t][0] = an[t][0]; cur[t][1] = an[t][1]; }
    #pragma unroll
    for (int t = 0; t < 4; ++t) {
      an[t][0] = *(const float4*)(xp + t * 16 * Dd + ktn);
      an[t][1] = *(const float4*)(xp + t * 16 * Dd + ktn + 4);
    }

    // compute: per row-tile split A into hi/lo then 4 col-tiles x 3 MFMAs
    #pragma unroll
    for (int t = 0; t < 4; ++t) {
      AFrag ahi, alo;
      split2(cur[t][0].x, cur[t][0].y, ahi.d[0], alo.d[0]);
      split2(cur[t][0].z, cur[t][0].w, ahi.d[1], alo.d[1]);
      split2(cur[t][1].x, cur[t][1].y, ahi.d[2], alo.d[2]);
      split2(cur[t][1].z, cur[t][1].w, ahi.d[3], alo.d[3]);
      #pragma unroll
      for (int ct = 0; ct < 4; ++ct) {
        acc[t][ct] = __builtin_amdgcn_mfma_f32_16x16x32_bf16(ahi.v, bh[ct].v, acc[t][ct], 0, 0, 0);
        acc[t][ct] = __builtin_amdgcn_mfma_f32_16x16x32_bf16(ahi.v, bl[ct].v, acc[t][ct], 0, 0, 0);
        acc[t][ct] = __builtin_amdgcn_mfma_f32_16x16x32_bf16(alo.v, bh[ct].v, acc[t][ct], 0, 0, 0);
      }
    }
  }

  // Epilogue per row-tile: logits rows r = quad*4+reg, cols c = ct*16+l15.
  float bia[4];
  #pragma unroll
  for (int ct = 0; ct < 4; ++ct) bia[ct] = bg[ct * 16 + l15];

  #pragma unroll
  for (int t = 0; t < 4; ++t) {
    #pragma unroll
    for (int reg = 0; reg < 4; ++reg) {
      float v[4];
      #pragma unroll
      for (int ct = 0; ct < 4; ++ct) v[ct] = acc[t][ct][reg] + bia[ct];

      // argmax over 64 cols: local over col-tiles (strict > keeps lowest c),
      // then butterfly over the 16-lane group (xor 1,2,4,8 stays in-group).
      float mx = v[0]; int mi = l15;
      #pragma unroll
      for (int ct = 1; ct < 4; ++ct) {
        int c = ct * 16 + l15;
        if (v[ct] > mx) { mx = v[ct]; mi = c; }
      }
      #pragma unroll
      for (int off = 1; off < 16; off <<= 1) {
        float om = __shfl_xor(mx, off);
        int   oi = __shfl_xor(mi, off);
        if (om > mx || (om == mx && oi < mi)) { mx = om; mi = oi; }
      }
      // softmax denominator
      float s = 0.f;
      #pragma unroll
      for (int ct = 0; ct < 4; ++ct) s += expf(v[ct] - mx);
      #pragma unroll
      for (int off = 1; off < 16; off <<= 1) s += __shfl_xor(s, off);

      if (l15 == 0) {   // this lane holds col 0 (v[0])
        size_t pr = prow + (size_t)t * 16 + (size_t)quad * 4 + reg;
        gate0[pr] = expf(v[0] - mx) / s;
        amax[pr]  = mi;
      }
    }
  }
}

// ---------------- kernel 2: per-batch coverage (NO atomics) ----------------
// Writes covg[b][e] = cov ? gate0[b,e] : 0, coalesced; covbits[b] for counts.
__global__ __launch_bounds__(64) void k_cov(const int* __restrict__ amax,
                                            const float* __restrict__ gate0,
                                            unsigned long long* __restrict__ covbits,
                                            float* __restrict__ covg) {
  int b = blockIdx.x;
  int lane = threadIdx.x;  // lane == seq-slot m in [0,64)
  __shared__ int idxs[Nn];
  idxs[lane]      = amax[(size_t)b * Nn + lane];
  idxs[lane + 64] = amax[(size_t)b * Nn + 64 + lane];
  __syncthreads();
  bool cov = false;
  #pragma unroll 8
  for (int n = 0; n < Nn; ++n) cov |= (idxs[n] == lane);
  unsigned long long bits = __ballot(cov);
  if (lane == 0) covbits[b] = bits;
  covg[(size_t)b * Ee + lane] = cov ? gate0[(size_t)b * Nn + lane] : 0.f;
}

// ---------------- kernel 2b: reduce covg over b -> denomS, cntS ----------------
__global__ __launch_bounds__(256) void k_reduce(const float* __restrict__ covg,
                                                const unsigned long long* __restrict__ covbits,
                                                float* __restrict__ denomS,
                                                float* __restrict__ cntS) {
  int e = blockIdx.x;       // expert / seq-slot [0,64)
  int t = threadIdx.x;
  float s = 0.f, c = 0.f;
  for (int b = t; b < Bb; b += 256) {
    s += covg[(size_t)b * Ee + e];
    c += (float)((covbits[b] >> e) & 1ull);
  }
  #pragma unroll
  for (int off = 1; off < 64; off <<= 1) {
    s += __shfl_xor(s, off);
    c += __shfl_xor(c, off);
  }
  __shared__ float ss[4], cs[4];
  int wave = t >> 6, lane = t & 63;
  if (lane == 0) { ss[wave] = s; cs[wave] = c; }
  __syncthreads();
  if (t == 0) {
    float S = 0.f, C = 0.f;
    #pragma unroll
    for (int i = 0; i < 4; ++i) { S += ss[i]; C += cs[i]; }
    denomS[e] = S;
    cntS[e] = C;
  }
}

// ---------------- kernel 3: scatter the covered gs values ----------------
__global__ __launch_bounds__(64) void k_scatter(const float* __restrict__ gate0,
                                                const unsigned long long* __restrict__ covbits,
                                                const float* __restrict__ denomS,
                                                float* __restrict__ out) {
  int b = blockIdx.x;
  int n = threadIdx.x;  // n < 64
  if ((covbits[b] >> n) & 1ull) {
    float g = gate0[(size_t)b * Nn + n];
    out[((size_t)(b * Nn + n)) * Ee] = g * 2048.0f / (denomS[n] + 1e-6f);
  }
}

// ---------------- kernel 4: closed-form cv^2 loss ----------------
__global__ __launch_bounds__(64) void k_loss(const float* __restrict__ denomS,
                                             const float* __restrict__ cntS,
                                             float* __restrict__ out) {
  int lane = threadIdx.x;
  double S = (double)denomS[lane];
  double imp = S / (S + 1e-6) * 2048.0;   // 0 when S==0
  double ld = (double)cntS[lane];
  double s1i = imp, s2i = imp * imp, s1l = ld, s2l = ld * ld;
  #pragma unroll
  for (int off = 1; off < 64; off <<= 1) {
    s1i += __shfl_xor(s1i, off);
    s2i += __shfl_xor(s2i, off);
    s1l += __shfl_xor(s1l, off);
    s2l += __shfl_xor(s2l, off);
  }
  if (lane == 0) {
    const double Nt = (double)(Nn * Ee);  // 8192 elements in [N,E]
    double mi_ = s1i / Nt;
    double vi  = (s2i - Nt * mi_ * mi_) / (Nt - 1.0);
    double li  = vi / (mi_ * mi_ + 1e-10);
    double ml_ = s1l / Nt;
    double vl  = (s2l - Nt * ml_ * ml_) / (Nt - 1.0);
    double ll_ = vl / (ml_ * ml_ + 1e-10);
    out[(size_t)Mm * Ee] = (float)(li + ll_);
  }
}

extern "C" void kernel_launch(void* const* d_in, const int* in_sizes, int n_in,
                              void* d_out, int out_size, void* d_ws, size_t ws_size,
                              hipStream_t stream) {
  const float* x  = (const float*)d_in[0];
  const float* w  = (const float*)d_in[1];
  const float* bg = (const float*)d_in[2];
  float* out = (float*)d_out;

  // Workspace layout (~2.7 MB total)
  char* ws = (char*)d_ws;
  float* gate0 = (float*)ws;                                      // 1 MB
  int*   amax  = (int*)(ws + (size_t)Mm * 4);                     // 1 MB
  unsigned long long* covbits =
      (unsigned long long*)(ws + (size_t)Mm * 8);                 // 16 KB
  float* denomS = (float*)(ws + (size_t)Mm * 8 + (size_t)Bb * 8); // 256 B
  float* cntS   = denomS + Ee;                                    // 256 B
  uint16_t* whi = (uint16_t*)(denomS + 2 * Ee);                   // 64 KB
  uint16_t* wlo = whi + Ee * Dd;                                  // 64 KB
  float* covg   = (float*)(wlo + Ee * Dd);                        // 512 KB

  k_packw<<<(Ee * Dd + 255) / 256, 256, 0, stream>>>(w, whi, wlo);
  k_main<<<Mm / 256, 256, 0, stream>>>(x, whi, wlo, bg, out, gate0, amax);
  k_cov<<<Bb, 64, 0, stream>>>(amax, gate0, covbits, covg);
  k_reduce<<<Ee, 256, 0, stream>>>(covg, covbits, denomS, cntS);
  k_scatter<<<Bb, 64, 0, stream>>>(gate0, covbits, denomS, out);
  k_loss<<<1, 64, 0, stream>>>(denomS, cntS, out);
}